// Round 1
// baseline (2160.901 us; speedup 1.0000x reference)
//
#include <hip/hip_runtime.h>
#include <hip/hip_bf16.h>

// Problem constants (Llama4TextExperts): E experts, hidden H, intermediate I, T tokens/expert
constexpr int kE = 16;
constexpr int kH = 2048;
constexpr int kI = 4096;
constexpr int kT = 512;

typedef __attribute__((ext_vector_type(8))) short bf16x8;  // 8 bf16 = 4 VGPRs (MFMA A/B frag)
typedef __attribute__((ext_vector_type(4))) float f32x4;   // MFMA C/D frag

__device__ __forceinline__ short f2bf(float f) {
  __hip_bfloat16 h = __float2bfloat16(f);
  return *reinterpret_cast<const short*>(&h);
}

__device__ __forceinline__ bf16x8 cvt8(const float4 p0, const float4 p1) {
  bf16x8 v;
  v[0] = f2bf(p0.x); v[1] = f2bf(p0.y); v[2] = f2bf(p0.z); v[3] = f2bf(p0.w);
  v[4] = f2bf(p1.x); v[5] = f2bf(p1.y); v[6] = f2bf(p1.z); v[7] = f2bf(p1.w);
  return v;
}

// ---------------------------------------------------------------------------
// Kernel 1: gate_up GEMM (C = x[e] @ gate_up_w[e]^T) + fused SiLU-gate.
// Block tile: 128 tokens x 64 intermediate cols, computing BOTH the gate tile
// (cols j0..j0+63) and the up tile (cols I+j0..I+j0+63) so the epilogue can
// form act = up * silu(gate) without materializing gate_up.
// 4 waves as 2x2; wave tile 64x32 per matrix -> acc[4][2] x2 = 64 acc regs.
// ---------------------------------------------------------------------------
__global__ __launch_bounds__(256, 2)
void k_gateup(const float* __restrict__ x,        // [E*T, H]
              const float* __restrict__ w,        // [E, 2I, H]
              __hip_bfloat16* __restrict__ act)   // [E, T, I]
{
  __shared__ short As[128 * 32];  // [row][k] bf16, BK=32
  __shared__ short Bg[64 * 32];
  __shared__ short Bu[64 * 32];

  const int e  = blockIdx.z;
  const int t0 = blockIdx.y * 128;
  const int j0 = blockIdx.x * 64;

  const int tid  = threadIdx.x;
  const int lane = tid & 63;
  const int wid  = tid >> 6;
  const int quad = lane >> 4;
  const int r16  = lane & 15;
  const int wm   = wid >> 1;  // 0..1
  const int wn   = wid & 1;   // 0..1

  const float* xA = x + (size_t)(e * kT + t0) * kH;
  const float* wG = w + (size_t)e * (2 * kI) * kH + (size_t)j0 * kH;
  const float* wU = wG + (size_t)kI * kH;

  f32x4 accg[4][2], accu[4][2];
#pragma unroll
  for (int i = 0; i < 4; ++i)
#pragma unroll
    for (int j = 0; j < 2; ++j) {
      accg[i][j] = (f32x4){0.f, 0.f, 0.f, 0.f};
      accu[i][j] = (f32x4){0.f, 0.f, 0.f, 0.f};
    }

  const int srow = tid >> 2;          // staging row (0..63)
  const int scol = (tid & 3) << 3;    // staging col: 0,8,16,24

  for (int k0 = 0; k0 < kH; k0 += 32) {
    // Stage A: 128x32 fp32 -> bf16 (512 chunks of 8; 2 per thread)
#pragma unroll
    for (int it = 0; it < 2; ++it) {
      int row = srow + it * 64;
      const float* src = xA + (size_t)row * kH + k0 + scol;
      float4 p0 = *(const float4*)src;
      float4 p1 = *(const float4*)(src + 4);
      *(bf16x8*)&As[row * 32 + scol] = cvt8(p0, p1);
    }
    // Stage Bg / Bu: 64x32 fp32 each -> bf16 (256 chunks each; 1 per thread)
    {
      const float* sg = wG + (size_t)srow * kH + k0 + scol;
      float4 g0 = *(const float4*)sg;
      float4 g1 = *(const float4*)(sg + 4);
      *(bf16x8*)&Bg[srow * 32 + scol] = cvt8(g0, g1);
      const float* su = wU + (size_t)srow * kH + k0 + scol;
      float4 u0 = *(const float4*)su;
      float4 u1 = *(const float4*)(su + 4);
      *(bf16x8*)&Bu[srow * 32 + scol] = cvt8(u0, u1);
    }
    __syncthreads();

    // Fragments: A[m=lane&15][k=quad*8+j]; B (=W row) same contiguous-K shape
    bf16x8 a[4], bg[2], bu[2];
#pragma unroll
    for (int mi = 0; mi < 4; ++mi)
      a[mi] = *(bf16x8*)&As[(wm * 64 + mi * 16 + r16) * 32 + quad * 8];
#pragma unroll
    for (int ni = 0; ni < 2; ++ni) {
      bg[ni] = *(bf16x8*)&Bg[(wn * 32 + ni * 16 + r16) * 32 + quad * 8];
      bu[ni] = *(bf16x8*)&Bu[(wn * 32 + ni * 16 + r16) * 32 + quad * 8];
    }
#pragma unroll
    for (int mi = 0; mi < 4; ++mi)
#pragma unroll
      for (int ni = 0; ni < 2; ++ni) {
        accg[mi][ni] = __builtin_amdgcn_mfma_f32_16x16x32_bf16(a[mi], bg[ni], accg[mi][ni], 0, 0, 0);
        accu[mi][ni] = __builtin_amdgcn_mfma_f32_16x16x32_bf16(a[mi], bu[ni], accu[mi][ni], 0, 0, 0);
      }
    __syncthreads();
  }

  // Epilogue: act = up * silu(gate), bf16 store.
  // C/D layout: col = lane&15, row = quad*4 + reg   [measured m89/m91]
  __hip_bfloat16* actE = act + (size_t)e * kT * kI;
#pragma unroll
  for (int mi = 0; mi < 4; ++mi)
#pragma unroll
    for (int ni = 0; ni < 2; ++ni)
#pragma unroll
      for (int rg = 0; rg < 4; ++rg) {
        int row = wm * 64 + mi * 16 + quad * 4 + rg;   // token within tile
        int col = j0 + wn * 32 + ni * 16 + r16;        // intermediate col
        float g = accg[mi][ni][rg];
        float u = accu[mi][ni][rg];
        float s = g / (1.f + __expf(-g));              // silu(g)
        actE[(size_t)(t0 + row) * kI + col] = __float2bfloat16(u * s);
      }
}

// ---------------------------------------------------------------------------
// Kernel 2: down GEMM: out[e] = act[e] (T x I, bf16) @ down_w[e]^T (H x I fp32)
// m97-style 128x128 tile, 4 waves 2x2, wave tile 64x64, acc[4][4].
// ---------------------------------------------------------------------------
__global__ __launch_bounds__(256, 2)
void k_down(const __hip_bfloat16* __restrict__ act,  // [E, T, I]
            const float* __restrict__ w,             // [E, H, I]
            float* __restrict__ out)                 // [E*T, H]
{
  __shared__ short As[128 * 32];
  __shared__ short Bs[128 * 32];

  const int e  = blockIdx.z;
  const int t0 = blockIdx.y * 128;
  const int h0 = blockIdx.x * 128;

  const int tid  = threadIdx.x;
  const int lane = tid & 63;
  const int wid  = tid >> 6;
  const int quad = lane >> 4;
  const int r16  = lane & 15;
  const int wm   = wid >> 1;
  const int wn   = wid & 1;

  const short* aA = (const short*)act + (size_t)(e * kT + t0) * kI;
  const float* wB = w + (size_t)e * kH * kI + (size_t)h0 * kI;

  f32x4 acc[4][4];
#pragma unroll
  for (int i = 0; i < 4; ++i)
#pragma unroll
    for (int j = 0; j < 4; ++j) acc[i][j] = (f32x4){0.f, 0.f, 0.f, 0.f};

  for (int k0 = 0; k0 < kI; k0 += 32) {
    // Stage A (bf16 raw copy) and B (fp32->bf16): 128x32 each, 512 chunks of 8
#pragma unroll
    for (int it = 0; it < 2; ++it) {
      int c = tid + it * 256;
      int row = c >> 2;
      int col = (c & 3) << 3;
      *(bf16x8*)&As[row * 32 + col] = *(const bf16x8*)(aA + (size_t)row * kI + k0 + col);
      const float* src = wB + (size_t)row * kI + k0 + col;
      float4 p0 = *(const float4*)src;
      float4 p1 = *(const float4*)(src + 4);
      *(bf16x8*)&Bs[row * 32 + col] = cvt8(p0, p1);
    }
    __syncthreads();

    bf16x8 a[4], b[4];
#pragma unroll
    for (int mi = 0; mi < 4; ++mi)
      a[mi] = *(bf16x8*)&As[(wm * 64 + mi * 16 + r16) * 32 + quad * 8];
#pragma unroll
    for (int ni = 0; ni < 4; ++ni)
      b[ni] = *(bf16x8*)&Bs[(wn * 64 + ni * 16 + r16) * 32 + quad * 8];
#pragma unroll
    for (int mi = 0; mi < 4; ++mi)
#pragma unroll
      for (int ni = 0; ni < 4; ++ni)
        acc[mi][ni] = __builtin_amdgcn_mfma_f32_16x16x32_bf16(a[mi], b[ni], acc[mi][ni], 0, 0, 0);
    __syncthreads();
  }

  // Epilogue: fp32 store to out[(e*T + t), h]
#pragma unroll
  for (int mi = 0; mi < 4; ++mi)
#pragma unroll
    for (int ni = 0; ni < 4; ++ni)
#pragma unroll
      for (int rg = 0; rg < 4; ++rg) {
        int row = wm * 64 + mi * 16 + quad * 4 + rg;
        int col = h0 + wn * 64 + ni * 16 + r16;
        out[(size_t)(e * kT + t0 + row) * kH + col] = acc[mi][ni][rg];
      }
}

extern "C" void kernel_launch(void* const* d_in, const int* in_sizes, int n_in,
                              void* d_out, int out_size, void* d_ws, size_t ws_size,
                              hipStream_t stream) {
  (void)in_sizes; (void)n_in; (void)out_size; (void)ws_size;
  const float* x  = (const float*)d_in[0];   // hidden_states [E*T, H] fp32
  const float* gw = (const float*)d_in[1];   // gate_up_w [E, 2I, H] fp32
  const float* dw = (const float*)d_in[2];   // down_w [E, H, I] fp32
  float* out = (float*)d_out;                // [E*T, H] fp32
  __hip_bfloat16* act = (__hip_bfloat16*)d_ws;  // [E, T, I] bf16 = 67 MB scratch

  dim3 g1(kI / 64, kT / 128, kE);    // (64, 4, 16)
  k_gateup<<<g1, dim3(256), 0, stream>>>(x, gw, act);

  dim3 g2(kH / 128, kT / 128, kE);   // (16, 4, 16)
  k_down<<<g2, dim3(256), 0, stream>>>(act, dw, out);
}